// Round 2
// baseline (515.650 us; speedup 1.0000x reference)
//
#include <hip/hip_runtime.h>
#include <hip/hip_bf16.h>
#include <cstdint>

// Custom vector types
typedef __attribute__((ext_vector_type(8))) short v8s;   // 8 x bf16 bits (4 VGPRs)
typedef __attribute__((ext_vector_type(4))) float v4f;   // MFMA accumulator

#define NUM_HEADS 8
#define D 256
#define TOK 25088              // 8*56*56 tokens
#define CCH 2048               // channels
#define STRIPS 32              // blocks per head
#define TILES_PER_STRIP 49     // 32*49 = 1568 = TOK/16 tiles per head

// float -> bf16 bits, round-to-nearest-even
__device__ __forceinline__ short f2bf(float f) {
  unsigned u = __builtin_bit_cast(unsigned, f);
  u = (u + 0x7FFFu + ((u >> 16) & 1u)) >> 16;
  return (short)u;
}

// ---------------------------------------------------------------------------
// Pack weight (8,256,256) fp32 -> fragment-ordered bf16 in d_ws (1 MiB).
// Unit: u = ((s*16 + j)*64 + lane) within head, 16 B each. Unit holds
// B[k = s*32 + (lane>>4)*8 + e][n = j*16 + (lane&15)], e=0..7 — exactly the
// mfma_f32_16x16x32_bf16 B fragment for (kstep s, ntile j).
// ---------------------------------------------------------------------------
__global__ __launch_bounds__(256) void pack_w(const float* __restrict__ w,
                                              short* __restrict__ p) {
  int idx  = blockIdx.x * 256 + threadIdx.x;  // 0..65535
  int lane = idx & 63;
  int j    = (idx >> 6) & 15;
  int s    = (idx >> 10) & 7;
  int head = idx >> 13;
  int n  = j * 16 + (lane & 15);
  int k0 = s * 32 + (lane >> 4) * 8;
  const float* src = w + head * 65536 + k0 * 256 + n;  // weight[head][k][n]
  v8s v;
#pragma unroll
  for (int e = 0; e < 8; ++e) v[e] = f2bf(src[e * 256]);
  *reinterpret_cast<v8s*>(p + (size_t)idx * 8) = v;
}

// Address-space helper types for global_load_lds
typedef __attribute__((address_space(1))) const unsigned int GAS;
typedef __attribute__((address_space(3))) unsigned int LAS;

// ---------------------------------------------------------------------------
// Main grouped GEMM. 256 blocks (1/CU), 512 threads = 8 waves.
// Block = (head, 49-tile token strip). Head's entire B (128 KB bf16,
// fragment-ordered) staged once into LDS; inner loop reads B via contiguous
// ds_read_b128 (no global latency in the MFMA chain). A panels (16 tok x 256 k
// fp32) prefetched one tile ahead so HBM latency hides under compute.
// ---------------------------------------------------------------------------
__global__ __launch_bounds__(512, 2) void grouped_mm(const float* __restrict__ x,
                                                     const short* __restrict__ pB,
                                                     float* __restrict__ out) {
  __shared__ short Bs[65536];  // 128 KiB: [(s*16+j)*64 + lane] * 8 bf16
  const int tid  = threadIdx.x;
  const int wave = tid >> 6;
  const int lane = tid & 63;
  const int head  = blockIdx.x >> 5;
  const int strip = blockIdx.x & 31;

  // ---- stage head's packed B into LDS: 8 waves x 16 KB, width-16 async ----
  {
    const char* src = (const char*)(pB + (size_t)head * 65536) + wave * 16384 + lane * 16;
    char*       dst = (char*)Bs + wave * 16384;
#pragma unroll
    for (int i = 0; i < 16; ++i) {
      __builtin_amdgcn_global_load_lds((GAS*)(src + i * 1024),
                                       (LAS*)(dst + i * 1024), 16, 0, 0);
    }
  }
  __syncthreads();  // drains vmcnt before barrier

  const int row = lane & 15;   // A-fragment row within 16-token tile
  const int kg  = lane >> 4;   // k-subgroup
  const float* abase = x + (size_t)head * D + (size_t)kg * 8 + (size_t)row * CCH;
  const int tile0 = strip * TILES_PER_STRIP;

  // ---- prefetch first A panel (16 independent dwordx4 per lane) ----
  v4f afp[8][2];
  {
    const float* ap = abase + (size_t)(tile0 + wave) * 16 * CCH;
#pragma unroll
    for (int s = 0; s < 8; ++s) {
      afp[s][0] = *reinterpret_cast<const v4f*>(ap + s * 32);
      afp[s][1] = *reinterpret_cast<const v4f*>(ap + s * 32 + 4);
    }
  }

  for (int i = wave; i < TILES_PER_STRIP; i += 8) {
    const int t0 = (tile0 + i) * 16;

    // convert current A panel to bf16 fragments (frees the fp32 regs)
    v8s af[8];
#pragma unroll
    for (int s = 0; s < 8; ++s) {
#pragma unroll
      for (int e = 0; e < 4; ++e) {
        af[s][e]     = f2bf(afp[s][0][e]);
        af[s][4 + e] = f2bf(afp[s][1][e]);
      }
    }

    // issue next tile's A loads (hide HBM latency under the MFMA loop)
    const int nx = i + 8;
    if (nx < TILES_PER_STRIP) {
      const float* ap = abase + (size_t)(tile0 + nx) * 16 * CCH;
#pragma unroll
      for (int s = 0; s < 8; ++s) {
        afp[s][0] = *reinterpret_cast<const v4f*>(ap + s * 32);
        afp[s][1] = *reinterpret_cast<const v4f*>(ap + s * 32 + 4);
      }
    }

    v4f acc[16];
#pragma unroll
    for (int j = 0; j < 16; ++j) acc[j] = (v4f){0.f, 0.f, 0.f, 0.f};

    const short* bs = Bs + (size_t)lane * 8;
#pragma unroll
    for (int s = 0; s < 8; ++s) {
#pragma unroll
      for (int j = 0; j < 16; ++j) {
        v8s bf_ = *reinterpret_cast<const v8s*>(bs + (size_t)(s * 16 + j) * 512);
        acc[j] = __builtin_amdgcn_mfma_f32_16x16x32_bf16(af[s], bf_, acc[j], 0, 0, 0);
      }
    }

    // C/D layout: col = lane&15, row = kg*4 + reg
    float* optr = out + (size_t)(t0 + kg * 4) * CCH + head * D + row;
#pragma unroll
    for (int j = 0; j < 16; ++j) {
#pragma unroll
      for (int r = 0; r < 4; ++r) {
        optr[(size_t)r * CCH + j * 16] = acc[j][r];
      }
    }
  }
}

extern "C" void kernel_launch(void* const* d_in, const int* in_sizes, int n_in,
                              void* d_out, int out_size, void* d_ws, size_t ws_size,
                              hipStream_t stream) {
  const float* x = (const float*)d_in[0];   // (8,56,56,2048) fp32
  const float* w = (const float*)d_in[1];   // (8,256,256) fp32
  float* out = (float*)d_out;               // (8,56,56,2048) fp32
  short* packed = (short*)d_ws;             // 1 MiB packed bf16 weights

  pack_w<<<256, 256, 0, stream>>>(w, packed);
  grouped_mm<<<NUM_HEADS * STRIPS, 512, 0, stream>>>(x, packed, out);
}

// Round 3
// 88.042 us; speedup vs baseline: 5.8568x; 5.8568x over previous
//
#include <hip/hip_runtime.h>
#include <hip/hip_bf16.h>
#include <cstdint>

typedef __attribute__((ext_vector_type(8))) short v8s;   // 8 x bf16 bits (4 VGPRs)
typedef __attribute__((ext_vector_type(4))) float v4f;   // 16B fp32 / MFMA acc

#define NUM_HEADS 8
#define D 256
#define CCH 2048               // channels
#define STRIPS 32              // blocks per head
#define TILES 49               // tiles (16 tokens) per strip: 32*49*16 = 25088

// float -> bf16 bits, round-to-nearest-even
__device__ __forceinline__ short f2bf(float f) {
  unsigned u = __builtin_bit_cast(unsigned, f);
  u = (u + 0x7FFFu + ((u >> 16) & 1u)) >> 16;
  return (short)u;
}

// ---------------------------------------------------------------------------
// Pack weight (8,256,256) fp32 -> fragment-ordered bf16 in d_ws (1 MiB).
// Unit u = (s*16 + j)*64 + lane within head, 16 B each:
// B[k = s*32 + (lane>>4)*8 + e][n = j*16 + (lane&15)], e = 0..7 — the
// mfma_f32_16x16x32_bf16 B fragment for (kstep s, ntile j).
// ---------------------------------------------------------------------------
__global__ __launch_bounds__(256) void pack_w(const float* __restrict__ w,
                                              short* __restrict__ p) {
  int idx  = blockIdx.x * 256 + threadIdx.x;  // 0..65535
  int lane = idx & 63;
  int j    = (idx >> 6) & 15;
  int s    = (idx >> 10) & 7;
  int head = idx >> 13;
  int n  = j * 16 + (lane & 15);
  int k0 = s * 32 + (lane >> 4) * 8;
  const float* src = w + head * 65536 + k0 * 256 + n;
  v8s v;
#pragma unroll
  for (int e = 0; e < 8; ++e) v[e] = f2bf(src[e * 256]);
  *reinterpret_cast<v8s*>(p + (size_t)idx * 8) = v;
}

typedef __attribute__((address_space(1))) const unsigned int GAS;
typedef __attribute__((address_space(3))) unsigned int LAS;

// ---------------------------------------------------------------------------
// Main grouped GEMM. 256 blocks (1/CU) x 1024 threads (16 waves, 4/SIMD).
// Block = (head, 49-tile strip). Waves = 8 n-groups x 2 m-tiles.
// B: register-resident per wave (2 ntiles x 8 ksteps, 64 VGPR), loaded once.
// A: double-buffered LDS, staged row-contiguous via global_load_lds (1 KB per
//    instruction), XOR-swizzled on the global source; ds_read_b128 with the
//    same XOR -> uniform bank spread. 2 tiles per period, 1 barrier/period.
// ---------------------------------------------------------------------------
__global__ __launch_bounds__(1024, 4) void grouped_mm(const float* __restrict__ x,
                                                      const short* __restrict__ pB,
                                                      float* __restrict__ out) {
  __shared__ alignas(16) char As[65536];  // [slot2][q2][row16][1024B]
  const int tid  = threadIdx.x;
  const int wv   = tid >> 6;          // wave id 0..15 (= staged row)
  const int lane = tid & 63;
  const int mt   = wv & 1;            // m-tile within pair
  const int ng   = wv >> 1;           // n-group (2 ntiles: 2ng, 2ng+1)
  const int head  = blockIdx.x >> 5;
  const int strip = blockIdx.x & 31;

  const int arow = lane & 15;         // fragment row
  const int kg   = lane >> 4;         // k subgroup

  // ---- persistent B fragments: 2 ntiles x 8 ksteps, 16 x 16B/lane ----
  v8s Bf0[8], Bf1[8];
  {
    const short* pb = pB + (size_t)head * 65536 + (size_t)lane * 8;
#pragma unroll
    for (int s = 0; s < 8; ++s) {
      Bf0[s] = *reinterpret_cast<const v8s*>(pb + (size_t)(s * 16 + 2 * ng)     * 512);
      Bf1[s] = *reinterpret_cast<const v8s*>(pb + (size_t)(s * 16 + 2 * ng + 1) * 512);
    }
  }

  // token row base for this block's strip (bytes into x)
  const char* xbase = (const char*)(x + (size_t)strip * TILES * 16 * CCH + head * D);
  const unsigned swz = (unsigned)((wv & 7) << 4);
  const unsigned lsw = ((unsigned)(lane * 16)) ^ swz;

  // stage row `wv` of tile t into (slot, q). 1 KB contiguous per instruction.
  auto stage = [&](int slot, int q, int t) {
    const char* g = xbase + ((size_t)(t * 16 + wv)) * (CCH * 4) ;
    char* l = As + (((slot * 2 + q) * 16 + wv) * 1024);
    __builtin_amdgcn_global_load_lds((GAS*)(g + lsw), (LAS*)l, 16, 0, 0);
  };

  // prologue: tiles 0,1 -> slot 0
  stage(0, 0, 0);
  stage(0, 1, 1);
  __syncthreads();  // drains vmcnt

  const unsigned rswz = (unsigned)((arow & 7) << 4);

  for (int p = 0; p < 25; ++p) {
    const int cur = p & 1;

    // issue next pair's staging first (latency hides under compute)
    const int tn = 2 * p + 2;
    if (tn < TILES)     stage(cur ^ 1, 0, tn);
    if (tn + 1 < TILES) stage(cur ^ 1, 1, tn + 1);

    const int myt = 2 * p + mt;
    if (myt < TILES) {
      const char* ar = As + (((cur * 2 + mt) * 16 + arow) * 1024);
      v4f acc0 = (v4f){0.f, 0.f, 0.f, 0.f};
      v4f acc1 = (v4f){0.f, 0.f, 0.f, 0.f};
#pragma unroll
      for (int s = 0; s < 8; ++s) {
        const unsigned q0 = ((unsigned)(s * 128 + kg * 32)) ^ rswz;
        v4f lo = *reinterpret_cast<const v4f*>(ar + q0);
        v4f hi = *reinterpret_cast<const v4f*>(ar + (q0 ^ 16u));
        v8s af;
#pragma unroll
        for (int e = 0; e < 4; ++e) {
          af[e]     = f2bf(lo[e]);
          af[4 + e] = f2bf(hi[e]);
        }
        acc0 = __builtin_amdgcn_mfma_f32_16x16x32_bf16(af, Bf0[s], acc0, 0, 0, 0);
        acc1 = __builtin_amdgcn_mfma_f32_16x16x32_bf16(af, Bf1[s], acc1, 0, 0, 0);
      }
      // C/D layout: col = lane&15, row = kg*4 + r
      float* op = out + (size_t)((strip * TILES + myt) * 16 + kg * 4) * CCH
                      + head * D + ng * 32 + (lane & 15);
#pragma unroll
      for (int r = 0; r < 4; ++r) {
        op[(size_t)r * CCH]      = acc0[r];
        op[(size_t)r * CCH + 16] = acc1[r];
      }
    }
    __syncthreads();
  }
}

extern "C" void kernel_launch(void* const* d_in, const int* in_sizes, int n_in,
                              void* d_out, int out_size, void* d_ws, size_t ws_size,
                              hipStream_t stream) {
  const float* x = (const float*)d_in[0];   // (8,56,56,2048) fp32
  const float* w = (const float*)d_in[1];   // (8,256,256) fp32
  float* out = (float*)d_out;               // (8,56,56,2048) fp32
  short* packed = (short*)d_ws;             // 1 MiB packed bf16 weights

  pack_w<<<256, 256, 0, stream>>>(w, packed);
  grouped_mm<<<NUM_HEADS * STRIPS, 1024, 0, stream>>>(x, packed, out);
}